// Round 1
// baseline (89.633 us; speedup 1.0000x reference)
//
#include <hip/hip_runtime.h>
#include <math.h>

// One block per image (B=1024 blocks, 256 threads). Thread p<196 simulates the
// 4-qubit circuit for patch p entirely in registers (16 complex amps), then the
// block reduces the 784-feature x W[10,784] GEMV via wave shuffles and thread 0
// applies log_softmax.

#define APPLY_RY(ST, cc, ss) do { \
  _Pragma("unroll") \
  for (int i = 0; i < 16; ++i) { \
    if (!(i & (ST))) { \
      float ar = sr[i], ai = si[i], br = sr[i + (ST)], bi = si[i + (ST)]; \
      sr[i]        = (cc) * ar - (ss) * br; \
      si[i]        = (cc) * ai - (ss) * bi; \
      sr[i + (ST)] = (ss) * ar + (cc) * br; \
      si[i + (ST)] = (ss) * ai + (cc) * bi; \
    } } } while (0)

// RZ(phi): bit0 amp *= (c, -s); bit1 amp *= (c, +s)   [c=cos(phi/2), s=sin(phi/2)]
#define APPLY_RZ(ST, cc, ss) do { \
  _Pragma("unroll") \
  for (int i = 0; i < 16; ++i) { \
    float m = (i & (ST)) ? (ss) : -(ss); \
    float ar = sr[i], ai = si[i]; \
    sr[i] = (cc) * ar - m * ai; \
    si[i] = (cc) * ai + m * ar; \
  } } while (0)

#define APPLY_CNOT(SC, ST) do { \
  _Pragma("unroll") \
  for (int i = 0; i < 16; ++i) { \
    if ((i & (SC)) && !(i & (ST))) { \
      float tr = sr[i], ti = si[i]; \
      sr[i] = sr[i + (ST)]; si[i] = si[i + (ST)]; \
      sr[i + (ST)] = tr;    si[i + (ST)] = ti; \
    } } } while (0)

__global__ __launch_bounds__(256) void quanv_fused_kernel(
    const float* __restrict__ x,    // (B,1,28,28)
    const float* __restrict__ qp,   // (L,4,3)
    const float* __restrict__ W,    // (10,784) row-major
    const float* __restrict__ bias, // (10,)
    float* __restrict__ out,        // (B,10)
    int L)
{
  const int n   = blockIdx.x;
  const int tid = threadIdx.x;
  const int p   = tid;            // patch index within image

  // Stage cos/sin of half-angles of q_params in LDS (shared by all patches).
  __shared__ float qc[48], qs[48];   // supports up to 4 layers
  const int nq = L * 12;
  if (tid < nq) {
    float s, c;
    sincosf(0.5f * qp[tid], &s, &c);
    qc[tid] = c; qs[tid] = s;
  }
  __syncthreads();

  float ez[4] = {0.f, 0.f, 0.f, 0.f};

  if (p < 196) {
    const int pr = p / 14, pcc = p % 14;
    const float* xb = x + (size_t)n * 784 + (2 * pr) * 28 + 2 * pcc;
    // patch angles, row-major (dr,dc): w0=(0,0) w1=(0,1) w2=(1,0) w3=(1,1)
    float ang0 = xb[0], ang1 = xb[1], ang2 = xb[28], ang3 = xb[29];
    float dc[4], ds[4];
    sincosf(0.5f * ang0, &ds[0], &dc[0]);
    sincosf(0.5f * ang1, &ds[1], &dc[1]);
    sincosf(0.5f * ang2, &ds[2], &dc[2]);
    sincosf(0.5f * ang3, &ds[3], &dc[3]);

    float sr[16], si[16];
#pragma unroll
    for (int i = 0; i < 16; ++i) { sr[i] = 0.f; si[i] = 0.f; }
    sr[0] = 1.f;

    for (int l = 0; l < L; ++l) {
      // data re-uploading RY on each wire (wire w -> stride 8>>w)
      APPLY_RY(8, dc[0], ds[0]);
      APPLY_RY(4, dc[1], ds[1]);
      APPLY_RY(2, dc[2], ds[2]);
      APPLY_RY(1, dc[3], ds[3]);
      // CNOT ring (0,1),(1,2),(2,3),(3,0)
      APPLY_CNOT(8, 4);
      APPLY_CNOT(4, 2);
      APPLY_CNOT(2, 1);
      APPLY_CNOT(1, 8);
      // per wire: RZ, RY, RZ with q_params[l, w, 0..2]
      const int base = l * 12;
      APPLY_RZ(8, qc[base + 0],  qs[base + 0]);
      APPLY_RY(8, qc[base + 1],  qs[base + 1]);
      APPLY_RZ(8, qc[base + 2],  qs[base + 2]);
      APPLY_RZ(4, qc[base + 3],  qs[base + 3]);
      APPLY_RY(4, qc[base + 4],  qs[base + 4]);
      APPLY_RZ(4, qc[base + 5],  qs[base + 5]);
      APPLY_RZ(2, qc[base + 6],  qs[base + 6]);
      APPLY_RY(2, qc[base + 7],  qs[base + 7]);
      APPLY_RZ(2, qc[base + 8],  qs[base + 8]);
      APPLY_RZ(1, qc[base + 9],  qs[base + 9]);
      APPLY_RY(1, qc[base + 10], qs[base + 10]);
      APPLY_RZ(1, qc[base + 11], qs[base + 11]);
    }

    // <Z_w> expectations
#pragma unroll
    for (int i = 0; i < 16; ++i) {
      float pp = sr[i] * sr[i] + si[i] * si[i];
      ez[0] += (i & 8) ? -pp : pp;
      ez[1] += (i & 4) ? -pp : pp;
      ez[2] += (i & 2) ? -pp : pp;
      ez[3] += (i & 1) ? -pp : pp;
    }
  }

  // Per-patch partial logits: feats[4p+w] * W[c, 4p+w]; W row base is 16B aligned.
  float part[10];
#pragma unroll
  for (int c = 0; c < 10; ++c) part[c] = 0.f;
  if (p < 196) {
    const float4* Wv = (const float4*)W;
#pragma unroll
    for (int c = 0; c < 10; ++c) {
      float4 wc = Wv[c * 196 + p];
      part[c] = ez[0] * wc.x + ez[1] * wc.y + ez[2] * wc.z + ez[3] * wc.w;
    }
  }

  // Reduce across the block: wave64 shuffle, then combine 4 waves in LDS.
  const int lane = tid & 63;
  const int wave = tid >> 6;
  __shared__ float red[4][10];
#pragma unroll
  for (int c = 0; c < 10; ++c) {
    float v = part[c];
#pragma unroll
    for (int off = 32; off > 0; off >>= 1) v += __shfl_down(v, off, 64);
    if (lane == 0) red[wave][c] = v;
  }
  __syncthreads();

  if (tid == 0) {
    float logits[10];
    float m = -1e30f;
#pragma unroll
    for (int c = 0; c < 10; ++c) {
      logits[c] = red[0][c] + red[1][c] + red[2][c] + red[3][c] + bias[c];
      m = fmaxf(m, logits[c]);
    }
    float sum = 0.f;
#pragma unroll
    for (int c = 0; c < 10; ++c) sum += expf(logits[c] - m);
    float lse = m + logf(sum);
#pragma unroll
    for (int c = 0; c < 10; ++c) out[(size_t)n * 10 + c] = logits[c] - lse;
  }
}

extern "C" void kernel_launch(void* const* d_in, const int* in_sizes, int n_in,
                              void* d_out, int out_size, void* d_ws, size_t ws_size,
                              hipStream_t stream) {
  const float* x    = (const float*)d_in[0];
  const float* qp   = (const float*)d_in[1];
  const float* W    = (const float*)d_in[2];
  const float* bias = (const float*)d_in[3];
  float* out        = (float*)d_out;

  const int B = in_sizes[0] / 784;   // 1024 images
  const int L = in_sizes[1] / 12;    // 3 layers

  quanv_fused_kernel<<<B, 256, 0, stream>>>(x, qp, W, bias, out, L);
}

// Round 2
// 81.990 us; speedup vs baseline: 1.0932x; 1.0932x over previous
//
#include <hip/hip_runtime.h>
#include <math.h>

// One block per image (B blocks, 256 threads). Thread p<196 simulates the
// 4-qubit circuit for patch p entirely in registers (16 complex amps).
// Optimizations vs v1:
//  - RZ*RY*RZ fused into one SU(2) matrix per (layer,wire), precomputed in LDS
//  - layer-1 peeled: data-RY on |0000> is a real product state (24 muls)
//  - __sincosf native trig (inputs are N(0,1)/2; threshold has 4x headroom)

#define APPLY_RY(ST, cc, ss) do { \
  _Pragma("unroll") \
  for (int i = 0; i < 16; ++i) { \
    if (!(i & (ST))) { \
      float ar = sr[i], ai = si[i], br = sr[i + (ST)], bi = si[i + (ST)]; \
      sr[i]        = (cc) * ar - (ss) * br; \
      si[i]        = (cc) * ai - (ss) * bi; \
      sr[i + (ST)] = (ss) * ar + (cc) * br; \
      si[i + (ST)] = (ss) * ai + (cc) * bi; \
    } } } while (0)

#define APPLY_CNOT(SC, ST) do { \
  _Pragma("unroll") \
  for (int i = 0; i < 16; ++i) { \
    if ((i & (SC)) && !(i & (ST))) { \
      float tr = sr[i], ti = si[i]; \
      sr[i] = sr[i + (ST)]; si[i] = si[i + (ST)]; \
      sr[i + (ST)] = tr;    si[i + (ST)] = ti; \
    } } } while (0)

// Fused U = RZ(p2)*RY(p1)*RZ(p0); u10=-conj(u01), u11=conj(u00).
// a' = u00*a + u01*b ; b' = -conj(u01)*a + conj(u00)*b
#define APPLY_U(ST, U0R, U0I, U1R, U1I) do { \
  _Pragma("unroll") \
  for (int i = 0; i < 16; ++i) { \
    if (!(i & (ST))) { \
      float ar = sr[i], ai = si[i], br = sr[i + (ST)], bi = si[i + (ST)]; \
      sr[i]        =  (U0R) * ar - (U0I) * ai + (U1R) * br - (U1I) * bi; \
      si[i]        =  (U0R) * ai + (U0I) * ar + (U1R) * bi + (U1I) * br; \
      sr[i + (ST)] = -(U1R) * ar - (U1I) * ai + (U0R) * br + (U0I) * bi; \
      si[i + (ST)] = -(U1R) * ai + (U1I) * ar + (U0R) * bi - (U0I) * br; \
    } } } while (0)

#define APPLY_U_LDS(ST, l, w) do { \
  const float* u_ = &uu[((l) * 4 + (w)) * 4]; \
  float u0r = u_[0], u0i = u_[1], u1r = u_[2], u1i = u_[3]; \
  APPLY_U(ST, u0r, u0i, u1r, u1i); \
} while (0)

#define LAYER_TAIL(l) do { \
  APPLY_CNOT(8, 4); APPLY_CNOT(4, 2); APPLY_CNOT(2, 1); APPLY_CNOT(1, 8); \
  APPLY_U_LDS(8, l, 0); APPLY_U_LDS(4, l, 1); APPLY_U_LDS(2, l, 2); APPLY_U_LDS(1, l, 3); \
} while (0)

#define DATA_RY_ALL() do { \
  APPLY_RY(8, dc[0], ds[0]); APPLY_RY(4, dc[1], ds[1]); \
  APPLY_RY(2, dc[2], ds[2]); APPLY_RY(1, dc[3], ds[3]); \
} while (0)

template <int LC>   // LC = compile-time layer count; 0 = runtime loop
__global__ __launch_bounds__(256, 4) void quanv_fused_kernel(
    const float* __restrict__ x,    // (B,1,28,28)
    const float* __restrict__ qp,   // (L,4,3)
    const float* __restrict__ W,    // (10,784) row-major
    const float* __restrict__ bias, // (10,)
    float* __restrict__ out,        // (B,10)
    int Lrt)
{
  const int L = (LC > 0) ? LC : Lrt;
  const int n   = blockIdx.x;
  const int tid = threadIdx.x;
  const int p   = tid;            // patch index within image

  // Precompute fused RZ*RY*RZ matrices (u00r,u00i,u01r,u01i) in LDS.
  __shared__ float uu[8 * 16];    // up to 8 layers * 4 wires * 4 floats
  if (tid < 4 * L) {
    const int l = tid >> 2, w = tid & 3;
    const float p0 = qp[l * 12 + w * 3 + 0];
    const float p1 = qp[l * 12 + w * 3 + 1];
    const float p2 = qp[l * 12 + w * 3 + 2];
    float c, s, ca, sa, cb, sb;
    __sincosf(0.5f * p1, &s, &c);
    __sincosf(0.5f * (p0 + p2), &sa, &ca);
    __sincosf(0.5f * (p0 - p2), &sb, &cb);
    float* u_ = &uu[(l * 4 + w) * 4];
    u_[0] =  c * ca;   // u00r
    u_[1] = -c * sa;   // u00i
    u_[2] = -s * cb;   // u01r
    u_[3] = -s * sb;   // u01i
  }
  __syncthreads();

  float ez[4] = {0.f, 0.f, 0.f, 0.f};

  if (p < 196) {
    const int pr = p / 14, pcc = p % 14;
    const float2* xb = (const float2*)(x + (size_t)n * 784 + (2 * pr) * 28 + 2 * pcc);
    float2 top = xb[0], bot = xb[14];   // row stride 28 floats = 14 float2
    float dc[4], ds[4];
    __sincosf(0.5f * top.x, &ds[0], &dc[0]);
    __sincosf(0.5f * top.y, &ds[1], &dc[1]);
    __sincosf(0.5f * bot.x, &ds[2], &dc[2]);
    __sincosf(0.5f * bot.y, &ds[3], &dc[3]);

    float sr[16], si[16];

    if (LC > 0) {
      // Layer 1 peeled: data-RY on |0000> is a real product state.
      float p00 = dc[0] * dc[1], p01 = dc[0] * ds[1];
      float p10 = ds[0] * dc[1], p11 = ds[0] * ds[1];
      float q00 = dc[2] * dc[3], q01 = dc[2] * ds[3];
      float q10 = ds[2] * dc[3], q11 = ds[2] * ds[3];
      float hi[4] = {p00, p01, p10, p11};
      float lo[4] = {q00, q01, q10, q11};
#pragma unroll
      for (int i = 0; i < 16; ++i) { sr[i] = hi[i >> 2] * lo[i & 3]; si[i] = 0.f; }
      LAYER_TAIL(0);
#pragma unroll
      for (int l = 1; l < ((LC > 0) ? LC : 1); ++l) {
        DATA_RY_ALL();
        LAYER_TAIL(l);
      }
    } else {
#pragma unroll
      for (int i = 0; i < 16; ++i) { sr[i] = 0.f; si[i] = 0.f; }
      sr[0] = 1.f;
      for (int l = 0; l < L; ++l) {
        DATA_RY_ALL();
        LAYER_TAIL(l);
      }
    }

    // <Z_w> expectations
#pragma unroll
    for (int i = 0; i < 16; ++i) {
      float pp = sr[i] * sr[i] + si[i] * si[i];
      ez[0] += (i & 8) ? -pp : pp;
      ez[1] += (i & 4) ? -pp : pp;
      ez[2] += (i & 2) ? -pp : pp;
      ez[3] += (i & 1) ? -pp : pp;
    }
  }

  // Per-patch partial logits: feats[4p+w] * W[c, 4p+w]; W row base is 16B aligned.
  float part[10];
#pragma unroll
  for (int c = 0; c < 10; ++c) part[c] = 0.f;
  if (p < 196) {
    const float4* Wv = (const float4*)W;
#pragma unroll
    for (int c = 0; c < 10; ++c) {
      float4 wc = Wv[c * 196 + p];
      part[c] = ez[0] * wc.x + ez[1] * wc.y + ez[2] * wc.z + ez[3] * wc.w;
    }
  }

  // Reduce across the block: wave64 shuffle, then combine 4 waves in LDS.
  const int lane = tid & 63;
  const int wave = tid >> 6;
  __shared__ float red[4][10];
#pragma unroll
  for (int c = 0; c < 10; ++c) {
    float v = part[c];
#pragma unroll
    for (int off = 32; off > 0; off >>= 1) v += __shfl_down(v, off, 64);
    if (lane == 0) red[wave][c] = v;
  }
  __syncthreads();

  if (tid == 0) {
    float logits[10];
    float m = -1e30f;
#pragma unroll
    for (int c = 0; c < 10; ++c) {
      logits[c] = red[0][c] + red[1][c] + red[2][c] + red[3][c] + bias[c];
      m = fmaxf(m, logits[c]);
    }
    float sum = 0.f;
#pragma unroll
    for (int c = 0; c < 10; ++c) sum += __expf(logits[c] - m);
    float lse = m + __logf(sum);
#pragma unroll
    for (int c = 0; c < 10; ++c) out[(size_t)n * 10 + c] = logits[c] - lse;
  }
}

extern "C" void kernel_launch(void* const* d_in, const int* in_sizes, int n_in,
                              void* d_out, int out_size, void* d_ws, size_t ws_size,
                              hipStream_t stream) {
  const float* x    = (const float*)d_in[0];
  const float* qp   = (const float*)d_in[1];
  const float* W    = (const float*)d_in[2];
  const float* bias = (const float*)d_in[3];
  float* out        = (float*)d_out;

  const int B = in_sizes[0] / 784;   // images
  const int L = in_sizes[1] / 12;    // layers

  switch (L) {
    case 1: quanv_fused_kernel<1><<<B, 256, 0, stream>>>(x, qp, W, bias, out, L); break;
    case 2: quanv_fused_kernel<2><<<B, 256, 0, stream>>>(x, qp, W, bias, out, L); break;
    case 3: quanv_fused_kernel<3><<<B, 256, 0, stream>>>(x, qp, W, bias, out, L); break;
    case 4: quanv_fused_kernel<4><<<B, 256, 0, stream>>>(x, qp, W, bias, out, L); break;
    default: quanv_fused_kernel<0><<<B, 256, 0, stream>>>(x, qp, W, bias, out, L); break;
  }
}